// Round 9
// baseline (246.079 us; speedup 1.0000x reference)
//
#include <hip/hip_runtime.h>
#include <cstdint>

// CIN chain: B=1024, F0=32, EMB=64, layers 128/128/128.
// cur[b,k,e] = sum_{i,j} x[b,i,e]*h[b,j,e]*W[i*fi+j,k]
//
// R22: 4 BLOCKS/CU VIA 2-PASS EXCHANGE. R21 (114.6, flat vs R20b):
// af-depth+setprio gave ~0 -> per-wave L2 latency not binding; the
// stable lever is block-level parallelism. LDS 47104 (24 KB XC) capped
// at 3 blocks/CU. Change: exchange in TWO 12 KB passes (pass1 combines
// rows 0..31 -> waves 0/1 epilogue; pass2 rows 32..63 -> waves 2/3),
// +2 barriers/phase. LDS 34816 -> 4 blocks/CU = 16 waves/CU (+33%).
// af back to 2-slot (R21 4-slot gave 0; keeps VGPR ~92 <= 128 so the
// 4th block is real). setprio kept. (256,4) honest for this shape.
// LDS: sX 4K | R_A 9216 | R_B 9216 | XC 12K  (34816 B)
//   R_A hT0(p40) -> [b1] -> hJ1(p72) -> [b1'] -> hJ2(p72)
//   R_B xJ(p72)  -> [b1] -> hT1(p72)
//   XC  slot(tgt,src) = (tgt*3+src)*1024 f16, reused across passes
// Barriers/phase: XW1; b1; XR1+EPI(w0,w1); b2; XW2; b3; XR2+EPI(w2,w3); B2.
// b1 also guarantees all kloop/sgemm reads of R_A/R_B done before EPI
// overwrites them.

typedef _Float16 half8  __attribute__((ext_vector_type(8)));
typedef _Float16 half4_ __attribute__((ext_vector_type(4)));
typedef _Float16 half2_ __attribute__((ext_vector_type(2)));
typedef float    f32x4  __attribute__((ext_vector_type(4)));

// Pack W (fan_in,128) f32 -> chunked f16 Wt[c][m][kk] = W[c*32+kk][m].
__global__ void pack_w_all(const float* __restrict__ W0, _Float16* __restrict__ Wt0,
                           const float* __restrict__ W1, _Float16* __restrict__ Wt1,
                           const float* __restrict__ W2, _Float16* __restrict__ Wt2)
{
    __shared__ _Float16 ldsT[128 * 33];
    const int blk = blockIdx.x, t = threadIdx.x;
    const float* W;
    _Float16* Wt;
    int c;
    if (blk < 32)       { W = W0; Wt = Wt0; c = blk; }
    else if (blk < 96)  { W = W1; Wt = Wt1; c = blk - 32; }
    else                { W = W2; Wt = Wt2; c = blk - 96; }

    for (int p = t; p < 32 * 128; p += 256) {
        int kk = p >> 7, m = p & 127;
        ldsT[m * 33 + kk] = (_Float16)W[(size_t)(c * 32 + kk) * 128 + m];
    }
    __syncthreads();
    int m = t >> 1, kk0 = (t & 1) * 16;
    half8 v0, v1;
#pragma unroll
    for (int i = 0; i < 8; ++i) {
        v0[i] = ldsT[m * 33 + kk0 + i];
        v1[i] = ldsT[m * 33 + kk0 + 8 + i];
    }
    *(half8*)(Wt + (size_t)c * 4096 + t * 16)     = v0;
    *(half8*)(Wt + (size_t)c * 4096 + t * 16 + 8) = v1;
}

// Templated kloop: ALL 64 hidden rows (mt=4), this wave's K-quarter.
// 2-slot dist-1 prefetch (R20b shape, VGPR ~92) + setprio on MFMA.
template<int NCH, int ISH, int PH>
__device__ __forceinline__ void kloop_t(f32x4 (&acc)[4][4],
    const _Float16* __restrict__ WtL, const _Float16* __restrict__ hb,
    const _Float16* __restrict__ sX, int lr, int q, int w)
{
#pragma unroll
    for (int mt = 0; mt < 4; ++mt)
#pragma unroll
        for (int nt = 0; nt < 4; ++nt)
            acc[mt][nt] = f32x4{0.0f, 0.0f, 0.0f, 0.0f};

    constexpr int HC = NCH / 4;               // chunks per wave (8 or 16)
    const int c0 = w * HC;
    const _Float16* aG = WtL + (size_t)c0 * 4096 + lr * 32 + q * 8;
    const _Float16* hP = hb + lr * PH + q * 8;
    const _Float16* xP = sX + lr;

    half8 afA[4], afB[4], hvA[4], hvB[4];
    _Float16 xsA[4], xsB[4];

    auto pf = [&](half8* af, half8* hv, _Float16* xs, int cc) {
        const int c  = c0 + cc;
        const int i  = c >> ISH;
        const int j0 = (c & ((1 << ISH) - 1)) << 5;
        const _Float16* ag = aG + (size_t)cc * 4096;
#pragma unroll
        for (int mt = 0; mt < 4; ++mt)
            af[mt] = *(const half8*)(ag + mt * 512);
        const _Float16* hh = hP + j0;
        const _Float16* xb = xP + (i << 6);
#pragma unroll
        for (int nt = 0; nt < 4; ++nt) {
            hv[nt] = *(const half8*)(hh + nt * (PH * 16));
            xs[nt] = xb[nt * 16];
        }
    };
    auto cp = [&](half8* af, half8* hv, _Float16* xs) {
        __builtin_amdgcn_s_setprio(1);
#pragma unroll
        for (int nt = 0; nt < 4; ++nt) {
            half2_ xv2 = {xs[nt], xs[nt]};
            half8 xv8 = __builtin_shufflevector(xv2, xv2, 0, 1, 0, 1, 0, 1, 0, 1);
            half8 bf = hv[nt] * xv8;
#pragma unroll
            for (int mt = 0; mt < 4; ++mt)
                acc[mt][nt] = __builtin_amdgcn_mfma_f32_16x16x32_f16(
                    af[mt], bf, acc[mt][nt], 0, 0, 0);
        }
        __builtin_amdgcn_s_setprio(0);
    };

    pf(afA, hvA, xsA, 0);
    for (int cc = 0; cc < HC; cc += 2) {
        pf(afB, hvB, xsB, cc + 1);
        cp(afA, hvA, xsA);
        if (cc + 2 < HC) pf(afA, hvA, xsA, cc + 2);
        cp(afB, hvB, xsB);
    }
}

// Fused hidden+S kernel. Block = 1 batch, 256 thr = 4 waves (K-quarter w).
__global__ __launch_bounds__(256, 4)
void cin_fused(const float* __restrict__ x,          // (1024,32,64) f32
               const _Float16* __restrict__ Wt0,
               const _Float16* __restrict__ Wt1,
               const float* __restrict__ bs0,
               const float* __restrict__ bs1,
               _Float16* __restrict__ S0,             // (1024,1024)
               _Float16* __restrict__ S1,             // (1024,2048)
               _Float16* __restrict__ S2)             // (1024,2048)
{
    __shared__ alignas(16) char smem[34816];
    _Float16* sX   = (_Float16*)smem;                  // 4 KB  [i*64+e]
    _Float16* R_A  = (_Float16*)(smem + 4096);         // 9216 B
    _Float16* R_B  = (_Float16*)(smem + 13312);        // 9216 B
    _Float16* XC16 = (_Float16*)(smem + 22528);        // 12 KB exchange

    const int t = threadIdx.x, lane = t & 63, w = t >> 6;
    const int lr = lane & 15, q = lane >> 4;
    const int b = blockIdx.x;

    // prologue: x -> sX [i][e]; xJ (pitch 72) -> R_B; hT0 (pitch 40) -> R_A
    {
        const float4* xv = (const float4*)(x + (size_t)b * 2048);
#pragma unroll
        for (int s = 0; s < 2; ++s) {
            int p4 = t + s * 256;
            float4 v = xv[p4];
            int idx = p4 * 4, i = idx >> 6, e0 = idx & 63;
            _Float16 h0 = (_Float16)v.x, h1 = (_Float16)v.y;
            _Float16 h2 = (_Float16)v.z, h3 = (_Float16)v.w;
            half4_ pk = {h0, h1, h2, h3};
            *(half4_*)(sX + i * 64 + e0) = pk;
            *(half4_*)(R_B + i * 72 + e0) = pk;
            R_A[(e0 + 0) * 40 + i] = h0;
            R_A[(e0 + 1) * 40 + i] = h1;
            R_A[(e0 + 2) * 40 + i] = h2;
            R_A[(e0 + 3) * 40 + i] = h3;
        }
    }
    __syncthreads();                                   // B0

    // persistent sgemm A-fragments, NAMED (it = w&1 folds into address)
    const int it = w & 1;
    const half8 aF0 = *(const half8*)(R_B + (it * 16 + lr) * 72 + q * 8);
    const half8 aF1 = *(const half8*)(R_B + (it * 16 + lr) * 72 + q * 8 + 32);

    f32x4 acc[4][4];

    // exchange helpers: slot(tgt,src) = (tgt*3+src)*1024 f16 (2 KB each)
    auto xw_pair = [&](const f32x4 (&a)[4], int slot) {
#pragma unroll
        for (int cc = 0; cc < 2; ++cc) {
            half8 hv8;
#pragma unroll
            for (int r = 0; r < 4; ++r) {
                hv8[r]     = (_Float16)a[cc * 2][r];
                hv8[4 + r] = (_Float16)a[cc * 2 + 1][r];
            }
            *(half8*)(XC16 + slot * 1024 + cc * 512 + lane * 8) = hv8;
        }
    };
    auto xr_sum = [&](f32x4 (&a)[4], int tgt) {
#pragma unroll
        for (int p = 0; p < 3; ++p) {
#pragma unroll
            for (int cc = 0; cc < 2; ++cc) {
                half8 hv8 = *(const half8*)(XC16 + (tgt * 3 + p) * 1024
                                            + cc * 512 + lane * 8);
#pragma unroll
                for (int r = 0; r < 4; ++r) {
                    a[cc * 2][r]     += (float)hv8[r];
                    a[cc * 2 + 1][r] += (float)hv8[4 + r];
                }
            }
        }
    };

    // epilogue for this wave's 16 rows (w*16 + q*4 ..)
    auto epi_rows = [&](const f32x4 (&a)[4], const float* bs,
                        _Float16* hJ, _Float16* hT, bool wantT) {
        const int jb = w * 16 + q * 4;
        const float b0f = bs[jb + 0], b1f = bs[jb + 1];
        const float b2f = bs[jb + 2], b3f = bs[jb + 3];
#pragma unroll
        for (int nt = 0; nt < 4; ++nt) {
            const int e = nt * 16 + lr;
            half4_ vh;
            vh[0] = (_Float16)(a[nt][0] + b0f);
            vh[1] = (_Float16)(a[nt][1] + b1f);
            vh[2] = (_Float16)(a[nt][2] + b2f);
            vh[3] = (_Float16)(a[nt][3] + b3f);
            hJ[(jb + 0) * 72 + e] = vh[0];
            hJ[(jb + 1) * 72 + e] = vh[1];
            hJ[(jb + 2) * 72 + e] = vh[2];
            hJ[(jb + 3) * 72 + e] = vh[3];
            if (wantT) *(half4_*)(hT + e * 72 + jb) = vh;
        }
    };

    // 2-pass combine+epilogue. Pass1: rows 0..31 (waves 0,1); pass2:
    // rows 32..63 (waves 2,3). XC reused; wave-uniform branches only.
    auto combine_epi = [&](const float* bs, _Float16* hJ, _Float16* hT,
                           bool wantT) {
        // pass1 writes: tgt0 <- w1,w2,w3 ; tgt1 <- w0,w2,w3
        if (w == 0)      { xw_pair(acc[1], 3); }
        else if (w == 1) { xw_pair(acc[0], 0); }
        else if (w == 2) { xw_pair(acc[0], 1); xw_pair(acc[1], 4); }
        else             { xw_pair(acc[0], 2); xw_pair(acc[1], 5); }
        __syncthreads();                             // b1
        if (w == 0)      { xr_sum(acc[0], 0); epi_rows(acc[0], bs, hJ, hT, wantT); }
        else if (w == 1) { xr_sum(acc[1], 1); epi_rows(acc[1], bs, hJ, hT, wantT); }
        __syncthreads();                             // b2
        // pass2 writes: tgt2 <- w0,w1,w3 ; tgt3 <- w0,w1,w2
        if (w == 0)      { xw_pair(acc[2], 0); xw_pair(acc[3], 3); }
        else if (w == 1) { xw_pair(acc[2], 1); xw_pair(acc[3], 4); }
        else if (w == 2) { xw_pair(acc[3], 5); }
        else             { xw_pair(acc[2], 2); }
        __syncthreads();                             // b3
        if (w == 2)      { xr_sum(acc[2], 0); epi_rows(acc[2], bs, hJ, hT, wantT); }
        else if (w == 3) { xr_sum(acc[3], 1); epi_rows(acc[3], bs, hJ, hT, wantT); }
    };

    // S_l[b][i*fi+j] = sum_e x[i,e]*h[j,e]; tiles split across 4 waves,
    // this wave's i-tile fixed = it (aF0/aF1), jt varies.
    auto sgemm = [&](const _Float16* hJ, int fi, _Float16* Sdst) {
        const int nT = fi >> 3;                        // 4 or 8 tiles
        for (int tt = w; tt < nT; tt += 4) {
            const int jt = tt >> 1;
            f32x4 sa = {0.0f, 0.0f, 0.0f, 0.0f};
            half8 bv0 = *(const half8*)(hJ + (jt * 16 + lr) * 72 + q * 8);
            half8 bv1 = *(const half8*)(hJ + (jt * 16 + lr) * 72 + q * 8 + 32);
            sa = __builtin_amdgcn_mfma_f32_16x16x32_f16(aF0, bv0, sa, 0, 0, 0);
            sa = __builtin_amdgcn_mfma_f32_16x16x32_f16(aF1, bv1, sa, 0, 0, 0);
#pragma unroll
            for (int r = 0; r < 4; ++r)
                Sdst[(size_t)b * (32 * fi) + (it * 16 + q * 4 + r) * fi
                     + jt * 16 + lr] = (_Float16)sa[r];
        }
    };

    // ---- phase 0 ----
    sgemm(R_B, 32, S0);                          // S0 = x @ x^T (B from xJ)
    kloop_t<32, 0, 40>(acc, Wt0, R_A, sX, lr, q, w);
    combine_epi(bs0, R_A, R_B, true);            // hJ1 -> R_A, hT1 -> R_B
    __syncthreads();                             // B2
    // ---- phase 1 ----
    sgemm(R_A, 64, S1);                          // S1 = x @ h1^T
    kloop_t<64, 1, 72>(acc, Wt1, R_B, sX, lr, q, w);
    combine_epi(bs1, R_A, nullptr, false);       // hJ2 -> R_A (hJ1 dead)
    __syncthreads();                             // B4
    sgemm(R_A, 64, S2);                          // S2 = x @ h2^T
}

// Direct-output GEMM: out[b, ob+k] = S_l[b,:] . Wt_l[:, dm0+k] + 64*bias.
// 1024 tasks, 1 task/block, 4-way K-split across waves; wave 0 combines.
__global__ __launch_bounds__(256, 4)
void cin_direct(const _Float16* __restrict__ S0v, const _Float16* __restrict__ S1v,
                const _Float16* __restrict__ S2v,
                const _Float16* __restrict__ Wt0, const _Float16* __restrict__ Wt1,
                const _Float16* __restrict__ Wt2,
                const float* __restrict__ bs0, const float* __restrict__ bs1,
                const float* __restrict__ bs2,
                float* __restrict__ out)
{
    __shared__ f32x4 red[3][64];
    const int t = threadIdx.x, lane = t & 63, kh = t >> 6;
    const int lr = lane & 15, q = lane >> 4;
    const int task = blockIdx.x;

    const _Float16 *S, *Wt;
    const float* bias;
    int fan, nch, dm0, ob, idx;
    if (task < 256)      { S = S0v; Wt = Wt0; bias = bs0; fan = 1024; nch = 32; dm0 = 64; ob = 0;   idx = task; }
    else if (task < 512) { S = S1v; Wt = Wt1; bias = bs1; fan = 2048; nch = 64; dm0 = 64; ob = 64;  idx = task - 256; }
    else                 { S = S2v; Wt = Wt2; bias = bs2; fan = 2048; nch = 64; dm0 = 0;  ob = 128; idx = task - 512; }
    const int bt = idx & 63, kt = idx >> 6;
    const int bbase = bt * 16;
    const int hq = nch >> 2, c0 = kh * hq;

    const _Float16* aG = Wt + (size_t)(dm0 + kt * 16 + lr) * 32 + q * 8
                            + (size_t)c0 * 4096;
    const _Float16* bG = S + (size_t)(bbase + lr) * fan + q * 8 + c0 * 32;

    f32x4 acc = {0.0f, 0.0f, 0.0f, 0.0f};
    half8 aA = *(const half8*)(aG);
    half8 bA = *(const half8*)(bG);
    for (int c = 0; c < hq; c += 2) {
        half8 aB = *(const half8*)(aG + (size_t)(c + 1) * 4096);
        half8 bB = *(const half8*)(bG + (c + 1) * 32);
        acc = __builtin_amdgcn_mfma_f32_16x16x32_f16(aA, bA, acc, 0, 0, 0);
        if (c + 2 < hq) {
            aA = *(const half8*)(aG + (size_t)(c + 2) * 4096);
            bA = *(const half8*)(bG + (c + 2) * 32);
        }
        acc = __builtin_amdgcn_mfma_f32_16x16x32_f16(aB, bB, acc, 0, 0, 0);
    }
    if (kh != 0) red[kh - 1][lane] = acc;
    __syncthreads();
    if (kh == 0) {
#pragma unroll
        for (int p = 0; p < 3; ++p) {
            f32x4 o = red[p][lane];
#pragma unroll
            for (int r = 0; r < 4; ++r) acc[r] += o[r];
        }
#pragma unroll
        for (int r = 0; r < 4; ++r) {
            int kl = kt * 16 + q * 4 + r;
            out[(size_t)(bbase + lr) * 256 + ob + kl]
                = acc[r] + 64.0f * bias[dm0 + kl];
        }
    }
}

extern "C" void kernel_launch(void* const* d_in, const int* in_sizes, int n_in,
                              void* d_out, int out_size, void* d_ws, size_t ws_size,
                              hipStream_t stream)
{
    const float* x  = (const float*)d_in[0];
    const float* W0 = (const float*)d_in[1];
    const float* b0 = (const float*)d_in[2];
    const float* W1 = (const float*)d_in[3];
    const float* b1 = (const float*)d_in[4];
    const float* W2 = (const float*)d_in[5];
    const float* b2 = (const float*)d_in[6];
    float* out = (float*)d_out;

    char* ws = (char*)d_ws;
    _Float16* Wt0 = (_Float16*)(ws + 0);           // 256 KB
    _Float16* Wt1 = (_Float16*)(ws + 262144);      // 512 KB
    _Float16* Wt2 = (_Float16*)(ws + 786432);      // 512 KB
    _Float16* S0  = (_Float16*)(ws + 1310720);     // 2 MB  (1024 x 1024 f16)
    _Float16* S1  = (_Float16*)(ws + 3407872);     // 4 MB  (1024 x 2048 f16)
    _Float16* S2  = (_Float16*)(ws + 7602176);     // 4 MB
    (void)in_sizes; (void)n_in; (void)out_size; (void)ws_size;

    hipLaunchKernelGGL(pack_w_all, dim3(160), dim3(256), 0, stream,
                       W0, Wt0, W1, Wt1, W2, Wt2);

    hipLaunchKernelGGL(cin_fused, dim3(1024), dim3(256), 0, stream,
                       x, Wt0, Wt1, b0, b1, S0, S1, S2);

    hipLaunchKernelGGL(cin_direct, dim3(1024), dim3(256), 0, stream,
                       S0, S1, S2, Wt0, Wt1, Wt2, b0, b1, b2, out);
}

// Round 11
// 118.385 us; speedup vs baseline: 2.0786x; 2.0786x over previous
//
#include <hip/hip_runtime.h>
#include <cstdint>

// CIN chain: B=1024, F0=32, EMB=64, layers 128/128/128.
// cur[b,k,e] = sum_{i,j} x[b,i,e]*h[b,j,e]*W[i*fi+j,k]
//
// R23b: resubmit of R23 (container infra failure, no counters).
// R22 STRUCTURE, (256,2) BOUND. R22 (246 us) was sabotaged by
// __launch_bounds__(256,4): allocator targets 512/(2*4)=64 VGPR
// (third occurrence: R16=60, R18=64, R22=64) and spills the ~115-reg
// live set to scratch -> 570 MB traffic (FETCH 121 + WRITE 449 MB).
// (256,2) variants allocate 72-92 VGPR and run clean (R17/R19/R20b/
// R21). ONE change vs R22: bound back to (256,2). Residency is
// resource-determined: VGPR <=128 (16-wave bracket) and LDS 34816*4
// = 139 KB < 160 KB -> 4 blocks/CU = 16 waves/CU, the occupancy R22
// was built to reach.
// Structure (unchanged from R22): 1 batch/block, 4 waves K-split-4,
// mt=4 kloop, named frags, 2-slot prefetch, setprio, 2-pass 12 KB
// f16 exchange (pass1 rows 0..31 -> waves 0/1; pass2 rows 32..63 ->
// waves 2/3), K-split-4 direct.
// LDS: sX 4K | R_A 9216 | R_B 9216 | XC 12K  (34816 B)
//   R_A hT0(p40) -> [b1] -> hJ1(p72) -> [b1'] -> hJ2(p72)
//   R_B xJ(p72)  -> [b1] -> hT1(p72)

typedef _Float16 half8  __attribute__((ext_vector_type(8)));
typedef _Float16 half4_ __attribute__((ext_vector_type(4)));
typedef _Float16 half2_ __attribute__((ext_vector_type(2)));
typedef float    f32x4  __attribute__((ext_vector_type(4)));

// Pack W (fan_in,128) f32 -> chunked f16 Wt[c][m][kk] = W[c*32+kk][m].
__global__ void pack_w_all(const float* __restrict__ W0, _Float16* __restrict__ Wt0,
                           const float* __restrict__ W1, _Float16* __restrict__ Wt1,
                           const float* __restrict__ W2, _Float16* __restrict__ Wt2)
{
    __shared__ _Float16 ldsT[128 * 33];
    const int blk = blockIdx.x, t = threadIdx.x;
    const float* W;
    _Float16* Wt;
    int c;
    if (blk < 32)       { W = W0; Wt = Wt0; c = blk; }
    else if (blk < 96)  { W = W1; Wt = Wt1; c = blk - 32; }
    else                { W = W2; Wt = Wt2; c = blk - 96; }

    for (int p = t; p < 32 * 128; p += 256) {
        int kk = p >> 7, m = p & 127;
        ldsT[m * 33 + kk] = (_Float16)W[(size_t)(c * 32 + kk) * 128 + m];
    }
    __syncthreads();
    int m = t >> 1, kk0 = (t & 1) * 16;
    half8 v0, v1;
#pragma unroll
    for (int i = 0; i < 8; ++i) {
        v0[i] = ldsT[m * 33 + kk0 + i];
        v1[i] = ldsT[m * 33 + kk0 + 8 + i];
    }
    *(half8*)(Wt + (size_t)c * 4096 + t * 16)     = v0;
    *(half8*)(Wt + (size_t)c * 4096 + t * 16 + 8) = v1;
}

// Templated kloop: ALL 64 hidden rows (mt=4), this wave's K-quarter.
// 2-slot dist-1 prefetch (VGPR ~92 shape) + setprio on MFMA.
template<int NCH, int ISH, int PH>
__device__ __forceinline__ void kloop_t(f32x4 (&acc)[4][4],
    const _Float16* __restrict__ WtL, const _Float16* __restrict__ hb,
    const _Float16* __restrict__ sX, int lr, int q, int w)
{
#pragma unroll
    for (int mt = 0; mt < 4; ++mt)
#pragma unroll
        for (int nt = 0; nt < 4; ++nt)
            acc[mt][nt] = f32x4{0.0f, 0.0f, 0.0f, 0.0f};

    constexpr int HC = NCH / 4;               // chunks per wave (8 or 16)
    const int c0 = w * HC;
    const _Float16* aG = WtL + (size_t)c0 * 4096 + lr * 32 + q * 8;
    const _Float16* hP = hb + lr * PH + q * 8;
    const _Float16* xP = sX + lr;

    half8 afA[4], afB[4], hvA[4], hvB[4];
    _Float16 xsA[4], xsB[4];

    auto pf = [&](half8* af, half8* hv, _Float16* xs, int cc) {
        const int c  = c0 + cc;
        const int i  = c >> ISH;
        const int j0 = (c & ((1 << ISH) - 1)) << 5;
        const _Float16* ag = aG + (size_t)cc * 4096;
#pragma unroll
        for (int mt = 0; mt < 4; ++mt)
            af[mt] = *(const half8*)(ag + mt * 512);
        const _Float16* hh = hP + j0;
        const _Float16* xb = xP + (i << 6);
#pragma unroll
        for (int nt = 0; nt < 4; ++nt) {
            hv[nt] = *(const half8*)(hh + nt * (PH * 16));
            xs[nt] = xb[nt * 16];
        }
    };
    auto cp = [&](half8* af, half8* hv, _Float16* xs) {
        __builtin_amdgcn_s_setprio(1);
#pragma unroll
        for (int nt = 0; nt < 4; ++nt) {
            half2_ xv2 = {xs[nt], xs[nt]};
            half8 xv8 = __builtin_shufflevector(xv2, xv2, 0, 1, 0, 1, 0, 1, 0, 1);
            half8 bf = hv[nt] * xv8;
#pragma unroll
            for (int mt = 0; mt < 4; ++mt)
                acc[mt][nt] = __builtin_amdgcn_mfma_f32_16x16x32_f16(
                    af[mt], bf, acc[mt][nt], 0, 0, 0);
        }
        __builtin_amdgcn_s_setprio(0);
    };

    pf(afA, hvA, xsA, 0);
    for (int cc = 0; cc < HC; cc += 2) {
        pf(afB, hvB, xsB, cc + 1);
        cp(afA, hvA, xsA);
        if (cc + 2 < HC) pf(afA, hvA, xsA, cc + 2);
        cp(afB, hvB, xsB);
    }
}

// Fused hidden+S kernel. Block = 1 batch, 256 thr = 4 waves (K-quarter w).
__global__ __launch_bounds__(256, 2)
void cin_fused(const float* __restrict__ x,          // (1024,32,64) f32
               const _Float16* __restrict__ Wt0,
               const _Float16* __restrict__ Wt1,
               const float* __restrict__ bs0,
               const float* __restrict__ bs1,
               _Float16* __restrict__ S0,             // (1024,1024)
               _Float16* __restrict__ S1,             // (1024,2048)
               _Float16* __restrict__ S2)             // (1024,2048)
{
    __shared__ alignas(16) char smem[34816];
    _Float16* sX   = (_Float16*)smem;                  // 4 KB  [i*64+e]
    _Float16* R_A  = (_Float16*)(smem + 4096);         // 9216 B
    _Float16* R_B  = (_Float16*)(smem + 13312);        // 9216 B
    _Float16* XC16 = (_Float16*)(smem + 22528);        // 12 KB exchange

    const int t = threadIdx.x, lane = t & 63, w = t >> 6;
    const int lr = lane & 15, q = lane >> 4;
    const int b = blockIdx.x;

    // prologue: x -> sX [i][e]; xJ (pitch 72) -> R_B; hT0 (pitch 40) -> R_A
    {
        const float4* xv = (const float4*)(x + (size_t)b * 2048);
#pragma unroll
        for (int s = 0; s < 2; ++s) {
            int p4 = t + s * 256;
            float4 v = xv[p4];
            int idx = p4 * 4, i = idx >> 6, e0 = idx & 63;
            _Float16 h0 = (_Float16)v.x, h1 = (_Float16)v.y;
            _Float16 h2 = (_Float16)v.z, h3 = (_Float16)v.w;
            half4_ pk = {h0, h1, h2, h3};
            *(half4_*)(sX + i * 64 + e0) = pk;
            *(half4_*)(R_B + i * 72 + e0) = pk;
            R_A[(e0 + 0) * 40 + i] = h0;
            R_A[(e0 + 1) * 40 + i] = h1;
            R_A[(e0 + 2) * 40 + i] = h2;
            R_A[(e0 + 3) * 40 + i] = h3;
        }
    }
    __syncthreads();                                   // B0

    // persistent sgemm A-fragments, NAMED (it = w&1 folds into address)
    const int it = w & 1;
    const half8 aF0 = *(const half8*)(R_B + (it * 16 + lr) * 72 + q * 8);
    const half8 aF1 = *(const half8*)(R_B + (it * 16 + lr) * 72 + q * 8 + 32);

    f32x4 acc[4][4];

    // exchange helpers: slot(tgt,src) = (tgt*3+src)*1024 f16 (2 KB each)
    auto xw_pair = [&](const f32x4 (&a)[4], int slot) {
#pragma unroll
        for (int cc = 0; cc < 2; ++cc) {
            half8 hv8;
#pragma unroll
            for (int r = 0; r < 4; ++r) {
                hv8[r]     = (_Float16)a[cc * 2][r];
                hv8[4 + r] = (_Float16)a[cc * 2 + 1][r];
            }
            *(half8*)(XC16 + slot * 1024 + cc * 512 + lane * 8) = hv8;
        }
    };
    auto xr_sum = [&](f32x4 (&a)[4], int tgt) {
#pragma unroll
        for (int p = 0; p < 3; ++p) {
#pragma unroll
            for (int cc = 0; cc < 2; ++cc) {
                half8 hv8 = *(const half8*)(XC16 + (tgt * 3 + p) * 1024
                                            + cc * 512 + lane * 8);
#pragma unroll
                for (int r = 0; r < 4; ++r) {
                    a[cc * 2][r]     += (float)hv8[r];
                    a[cc * 2 + 1][r] += (float)hv8[4 + r];
                }
            }
        }
    };

    // epilogue for this wave's 16 rows (w*16 + q*4 ..)
    auto epi_rows = [&](const f32x4 (&a)[4], const float* bs,
                        _Float16* hJ, _Float16* hT, bool wantT) {
        const int jb = w * 16 + q * 4;
        const float b0f = bs[jb + 0], b1f = bs[jb + 1];
        const float b2f = bs[jb + 2], b3f = bs[jb + 3];
#pragma unroll
        for (int nt = 0; nt < 4; ++nt) {
            const int e = nt * 16 + lr;
            half4_ vh;
            vh[0] = (_Float16)(a[nt][0] + b0f);
            vh[1] = (_Float16)(a[nt][1] + b1f);
            vh[2] = (_Float16)(a[nt][2] + b2f);
            vh[3] = (_Float16)(a[nt][3] + b3f);
            hJ[(jb + 0) * 72 + e] = vh[0];
            hJ[(jb + 1) * 72 + e] = vh[1];
            hJ[(jb + 2) * 72 + e] = vh[2];
            hJ[(jb + 3) * 72 + e] = vh[3];
            if (wantT) *(half4_*)(hT + e * 72 + jb) = vh;
        }
    };

    // 2-pass combine+epilogue. Pass1: rows 0..31 (waves 0,1); pass2:
    // rows 32..63 (waves 2,3). XC reused; wave-uniform branches only.
    auto combine_epi = [&](const float* bs, _Float16* hJ, _Float16* hT,
                           bool wantT) {
        // pass1 writes: tgt0 <- w1,w2,w3 ; tgt1 <- w0,w2,w3
        if (w == 0)      { xw_pair(acc[1], 3); }
        else if (w == 1) { xw_pair(acc[0], 0); }
        else if (w == 2) { xw_pair(acc[0], 1); xw_pair(acc[1], 4); }
        else             { xw_pair(acc[0], 2); xw_pair(acc[1], 5); }
        __syncthreads();                             // b1
        if (w == 0)      { xr_sum(acc[0], 0); epi_rows(acc[0], bs, hJ, hT, wantT); }
        else if (w == 1) { xr_sum(acc[1], 1); epi_rows(acc[1], bs, hJ, hT, wantT); }
        __syncthreads();                             // b2
        // pass2 writes: tgt2 <- w0,w1,w3 ; tgt3 <- w0,w1,w2
        if (w == 0)      { xw_pair(acc[2], 0); xw_pair(acc[3], 3); }
        else if (w == 1) { xw_pair(acc[2], 1); xw_pair(acc[3], 4); }
        else if (w == 2) { xw_pair(acc[3], 5); }
        else             { xw_pair(acc[2], 2); }
        __syncthreads();                             // b3
        if (w == 2)      { xr_sum(acc[2], 0); epi_rows(acc[2], bs, hJ, hT, wantT); }
        else if (w == 3) { xr_sum(acc[3], 1); epi_rows(acc[3], bs, hJ, hT, wantT); }
    };

    // S_l[b][i*fi+j] = sum_e x[i,e]*h[j,e]; tiles split across 4 waves,
    // this wave's i-tile fixed = it (aF0/aF1), jt varies.
    auto sgemm = [&](const _Float16* hJ, int fi, _Float16* Sdst) {
        const int nT = fi >> 3;                        // 4 or 8 tiles
        for (int tt = w; tt < nT; tt += 4) {
            const int jt = tt >> 1;
            f32x4 sa = {0.0f, 0.0f, 0.0f, 0.0f};
            half8 bv0 = *(const half8*)(hJ + (jt * 16 + lr) * 72 + q * 8);
            half8 bv1 = *(const half8*)(hJ + (jt * 16 + lr) * 72 + q * 8 + 32);
            sa = __builtin_amdgcn_mfma_f32_16x16x32_f16(aF0, bv0, sa, 0, 0, 0);
            sa = __builtin_amdgcn_mfma_f32_16x16x32_f16(aF1, bv1, sa, 0, 0, 0);
#pragma unroll
            for (int r = 0; r < 4; ++r)
                Sdst[(size_t)b * (32 * fi) + (it * 16 + q * 4 + r) * fi
                     + jt * 16 + lr] = (_Float16)sa[r];
        }
    };

    // ---- phase 0 ----
    sgemm(R_B, 32, S0);                          // S0 = x @ x^T (B from xJ)
    kloop_t<32, 0, 40>(acc, Wt0, R_A, sX, lr, q, w);
    combine_epi(bs0, R_A, R_B, true);            // hJ1 -> R_A, hT1 -> R_B
    __syncthreads();                             // B2
    // ---- phase 1 ----
    sgemm(R_A, 64, S1);                          // S1 = x @ h1^T
    kloop_t<64, 1, 72>(acc, Wt1, R_B, sX, lr, q, w);
    combine_epi(bs1, R_A, nullptr, false);       // hJ2 -> R_A (hJ1 dead)
    __syncthreads();                             // B4
    sgemm(R_A, 64, S2);                          // S2 = x @ h2^T
}

// Direct-output GEMM: out[b, ob+k] = S_l[b,:] . Wt_l[:, dm0+k] + 64*bias.
// 1024 tasks, 1 task/block, 4-way K-split across waves; wave 0 combines.
__global__ __launch_bounds__(256, 2)
void cin_direct(const _Float16* __restrict__ S0v, const _Float16* __restrict__ S1v,
                const _Float16* __restrict__ S2v,
                const _Float16* __restrict__ Wt0, const _Float16* __restrict__ Wt1,
                const _Float16* __restrict__ Wt2,
                const float* __restrict__ bs0, const float* __restrict__ bs1,
                const float* __restrict__ bs2,
                float* __restrict__ out)
{
    __shared__ f32x4 red[3][64];
    const int t = threadIdx.x, lane = t & 63, kh = t >> 6;
    const int lr = lane & 15, q = lane >> 4;
    const int task = blockIdx.x;

    const _Float16 *S, *Wt;
    const float* bias;
    int fan, nch, dm0, ob, idx;
    if (task < 256)      { S = S0v; Wt = Wt0; bias = bs0; fan = 1024; nch = 32; dm0 = 64; ob = 0;   idx = task; }
    else if (task < 512) { S = S1v; Wt = Wt1; bias = bs1; fan = 2048; nch = 64; dm0 = 64; ob = 64;  idx = task - 256; }
    else                 { S = S2v; Wt = Wt2; bias = bs2; fan = 2048; nch = 64; dm0 = 0;  ob = 128; idx = task - 512; }
    const int bt = idx & 63, kt = idx >> 6;
    const int bbase = bt * 16;
    const int hq = nch >> 2, c0 = kh * hq;

    const _Float16* aG = Wt + (size_t)(dm0 + kt * 16 + lr) * 32 + q * 8
                            + (size_t)c0 * 4096;
    const _Float16* bG = S + (size_t)(bbase + lr) * fan + q * 8 + c0 * 32;

    f32x4 acc = {0.0f, 0.0f, 0.0f, 0.0f};
    half8 aA = *(const half8*)(aG);
    half8 bA = *(const half8*)(bG);
    for (int c = 0; c < hq; c += 2) {
        half8 aB = *(const half8*)(aG + (size_t)(c + 1) * 4096);
        half8 bB = *(const half8*)(bG + (c + 1) * 32);
        acc = __builtin_amdgcn_mfma_f32_16x16x32_f16(aA, bA, acc, 0, 0, 0);
        if (c + 2 < hq) {
            aA = *(const half8*)(aG + (size_t)(c + 2) * 4096);
            bA = *(const half8*)(bG + (c + 2) * 32);
        }
        acc = __builtin_amdgcn_mfma_f32_16x16x32_f16(aB, bB, acc, 0, 0, 0);
    }
    if (kh != 0) red[kh - 1][lane] = acc;
    __syncthreads();
    if (kh == 0) {
#pragma unroll
        for (int p = 0; p < 3; ++p) {
            f32x4 o = red[p][lane];
#pragma unroll
            for (int r = 0; r < 4; ++r) acc[r] += o[r];
        }
#pragma unroll
        for (int r = 0; r < 4; ++r) {
            int kl = kt * 16 + q * 4 + r;
            out[(size_t)(bbase + lr) * 256 + ob + kl]
                = acc[r] + 64.0f * bias[dm0 + kl];
        }
    }
}

extern "C" void kernel_launch(void* const* d_in, const int* in_sizes, int n_in,
                              void* d_out, int out_size, void* d_ws, size_t ws_size,
                              hipStream_t stream)
{
    const float* x  = (const float*)d_in[0];
    const float* W0 = (const float*)d_in[1];
    const float* b0 = (const float*)d_in[2];
    const float* W1 = (const float*)d_in[3];
    const float* b1 = (const float*)d_in[4];
    const float* W2 = (const float*)d_in[5];
    const float* b2 = (const float*)d_in[6];
    float* out = (float*)d_out;

    char* ws = (char*)d_ws;
    _Float16* Wt0 = (_Float16*)(ws + 0);           // 256 KB
    _Float16* Wt1 = (_Float16*)(ws + 262144);      // 512 KB
    _Float16* Wt2 = (_Float16*)(ws + 786432);      // 512 KB
    _Float16* S0  = (_Float16*)(ws + 1310720);     // 2 MB  (1024 x 1024 f16)
    _Float16* S1  = (_Float16*)(ws + 3407872);     // 4 MB  (1024 x 2048 f16)
    _Float16* S2  = (_Float16*)(ws + 7602176);     // 4 MB
    (void)in_sizes; (void)n_in; (void)out_size; (void)ws_size;

    hipLaunchKernelGGL(pack_w_all, dim3(160), dim3(256), 0, stream,
                       W0, Wt0, W1, Wt1, W2, Wt2);

    hipLaunchKernelGGL(cin_fused, dim3(1024), dim3(256), 0, stream,
                       x, Wt0, Wt1, b0, b1, S0, S1, S2);

    hipLaunchKernelGGL(cin_direct, dim3(1024), dim3(256), 0, stream,
                       S0, S1, S2, Wt0, Wt1, Wt2, b0, b1, b2, out);
}